// Round 10
// baseline (199.944 us; speedup 1.0000x reference)
//
#include <hip/hip_runtime.h>
#include <hip/hip_bf16.h>

#define NNODES 20000
#define NE_RAW 200000
#define MAX1   128
#define MAXE2  256
#define FIN    1280
#define FH     1024
#define NHEAD  4
#define C2     128
#define CAPE   512
#define KCK    64
#define NKC    20
#define E2CAP  32
#define NSCAN  196           // 196 * 1024 >= 200000 edges
#define NREG   (NSCAN + 1)   // +1 region for the mi self-loop
#define B_WATT 40
#define B_PMD  4
#define B_HZ   16
#define PRE_B  (B_WATT + NSCAN + B_PMD + B_HZ)
#define D_B    160           // 20 kc x 8 ct

__device__ __forceinline__ float lrelu(float x){ return x >= 0.f ? x : 0.2f * x; }

// Deterministic S1 derivation from E2raw bytes (same algorithm in every consumer).
__device__ int derive_S1(const int* __restrict__ E2cnt, const int* __restrict__ E2raw,
                         int* S1l){
  int n1 = 0;
  for (int b = 0; b < NREG; ++b){
    int c = E2cnt[b];
    if (c < 0) c = 0; if (c > E2CAP) c = E2CAP;
    for (int s = 0; s < c; ++s){
      int v = E2raw[b * E2CAP + s];
      bool found = false;
      for (int k = 0; k < n1; ++k) if (S1l[k] == v){ found = true; break; }
      if (!found && n1 < MAX1) S1l[n1++] = v;
    }
  }
  return n1;
}

// K0 (k_pre): w_att fold | edge scan -> E2 regions | pmd GEMV + self-loop | h1 zero
__global__ __launch_bounds__(256) void k_pre(
    const int* __restrict__ ei, const int* __restrict__ mip,
    const float* __restrict__ W1, const float* __restrict__ as1,
    const float* __restrict__ ad1,
    const float* __restrict__ msd, const float* __restrict__ Wm1,
    const float* __restrict__ bm1,
    int* __restrict__ E2cnt, int* __restrict__ E2raw,
    float* __restrict__ w_att, float* __restrict__ r1,
    float4* __restrict__ h1z){
  int b = blockIdx.x, t = threadIdx.x;
  if (b < B_WATT){
    // w_att[k][0..3] = W1[k,:]·as1 per head ; [4..7] = ·ad1. Wave per 8 rows.
    int w = t >> 6, lane = t & 63;
    float av[16], dv[16];
    #pragma unroll
    for (int i = 0; i < 16; ++i){ av[i] = as1[lane + 64 * i]; dv[i] = ad1[lane + 64 * i]; }
    int kbase = (b * 4 + w) * 8;
    for (int rr = 0; rr < 8; ++rr){
      int k = kbase + rr;
      const float* Wr = W1 + (long)k * FH;
      float wv[16];
      #pragma unroll
      for (int i = 0; i < 16; ++i) wv[i] = Wr[lane + 64 * i];
      float s[8];
      #pragma unroll
      for (int h = 0; h < 4; ++h){
        float sa = 0.f, sd = 0.f;
        #pragma unroll
        for (int i = 4 * h; i < 4 * h + 4; ++i){ sa += wv[i] * av[i]; sd += wv[i] * dv[i]; }
        s[h] = sa; s[4 + h] = sd;
      }
      #pragma unroll
      for (int q = 0; q < 8; ++q){
        float v = s[q];
        #pragma unroll
        for (int o = 32; o; o >>= 1) v += __shfl_xor(v, o, 64);
        if (lane == 0) w_att[(long)k * 8 + q] = v;
      }
    }
    return;
  }
  if (b < B_WATT + NSCAN){
    // counter-free scan1: per-block private E2 region
    __shared__ int lcnt;
    __shared__ int lbuf[E2CAP];
    int sb = b - B_WATT;
    if (t == 0) lcnt = 0;
    __syncthreads();
    int mi = mip[0];
    int e0 = sb * 1024 + t * 4;
    if (e0 < NE_RAW){
      int4 s4 = *(const int4*)(ei + e0);
      int4 d4 = *(const int4*)(ei + NE_RAW + e0);
      int ss[4] = { s4.x, s4.y, s4.z, s4.w };
      int dd[4] = { d4.x, d4.y, d4.z, d4.w };
      #pragma unroll
      for (int q = 0; q < 4; ++q){
        if (dd[q] == mi){
          int p = atomicAdd(&lcnt, 1);
          if (p < E2CAP) lbuf[p] = ss[q];
        }
      }
    }
    __syncthreads();
    int c = lcnt; if (c > E2CAP) c = E2CAP;
    if (t == 0) E2cnt[sb] = c;
    if (t < c) E2raw[sb * E2CAP + t] = lbuf[t];
    return;
  }
  if (b < B_WATT + NSCAN + B_PMD){
    __shared__ float red[256];
    int pb  = b - B_WATT - NSCAN;            // 0..3
    if (pb == 0 && t == 0){                  // mi self-loop -> last region
      E2cnt[NSCAN] = 1;
      E2raw[NSCAN * E2CAP] = mip[0];
    }
    int col = pb * 32 + (t & 31);
    int sl  = t >> 5;
    float s = 0.f;
    for (int k = sl * 128; k < sl * 128 + 128; ++k)
      s += msd[k] * Wm1[k * C2 + col];
    red[t] = s;
    __syncthreads();
    if (t < 32){
      float v = 0.f;
      #pragma unroll
      for (int q = 0; q < 8; ++q) v += red[q * 32 + t];
      v += bm1[col];
      r1[col] = v > 0.f ? v : 0.f;
    }
    return;
  }
  // zero h1 (atomic accumulation target): MAX1*FH floats = 32768 float4
  {
    int zb = b - B_WATT - NSCAN - B_PMD;     // 0..15
    float4 z = make_float4(0.f, 0.f, 0.f, 0.f);
    int base = zb * 2048 + t;
    #pragma unroll
    for (int i = 0; i < 8; ++i) h1z[base + 256 * i] = z;
  }
}

// K1 (k_bc): per S1 node: find edges by scanning ei, logits, softmax, aggregate -> X1
__global__ __launch_bounds__(256) void k_bc(
    const float* __restrict__ x, const int* __restrict__ ei,
    const float* __restrict__ w_att,
    const int* __restrict__ E2cnt, const int* __restrict__ E2raw,
    float* __restrict__ X1){
  __shared__ int   S1l[MAX1];
  __shared__ int   n1s;
  __shared__ int   lsrc[CAPE];
  __shared__ float ev[NHEAD][CAPE];
  __shared__ float adml[NHEAD];
  __shared__ float redl[4][4];
  __shared__ int   scnt;
  int t = threadIdx.x, w = t >> 6, lane = t & 63;
  if (t == 0) n1s = derive_S1(E2cnt, E2raw, S1l);
  __syncthreads();
  int n1 = n1s;
  for (int j = blockIdx.x; j < n1; j += gridDim.x){
    int s = S1l[j];
    __syncthreads();
    if (t == 0) scnt = 0;
    __syncthreads();
    // collect edge occurrences into s by scanning the raw edge list
    for (int base = t * 4; base < NE_RAW; base += 1024){
      int4 s4 = *(const int4*)(ei + base);
      int4 d4 = *(const int4*)(ei + NE_RAW + base);
      int ss[4] = { s4.x, s4.y, s4.z, s4.w };
      int dd[4] = { d4.x, d4.y, d4.z, d4.w };
      #pragma unroll
      for (int q = 0; q < 4; ++q){
        if (dd[q] == s){
          int p = atomicAdd(&scnt, 1);
          if (p < CAPE) lsrc[p] = ss[q];
        }
      }
    }
    if (t == 0){                              // self-loop s -> s
      int p = atomicAdd(&scnt, 1);
      if (p < CAPE) lsrc[p] = s;
    }
    __syncthreads();
    int ce = scnt; if (ce > CAPE) ce = CAPE;
    // a_dst: block-wide dot x[s]·w_att[.,4..7]
    {
      const float* xs = x + (long)s * FIN;
      float a0=0.f, a1=0.f, a2=0.f, a3=0.f;
      #pragma unroll
      for (int i = 0; i < 5; ++i){
        int k = t + 256 * i;
        float xv = xs[k];
        float4 wd = *(const float4*)(w_att + k * 8 + 4);
        a0 += xv * wd.x; a1 += xv * wd.y; a2 += xv * wd.z; a3 += xv * wd.w;
      }
      float v[4] = { a0, a1, a2, a3 };
      #pragma unroll
      for (int q = 0; q < 4; ++q){
        float sv = v[q];
        #pragma unroll
        for (int o = 32; o; o >>= 1) sv += __shfl_xor(sv, o, 64);
        if (lane == 0) redl[w][q] = sv;
      }
      __syncthreads();
      if (t < 4) adml[t] = redl[0][t] + redl[1][t] + redl[2][t] + redl[3][t];
      __syncthreads();
    }
    // per-edge a_src (wave-per-edge)
    for (int e = w; e < ce; e += 4){
      const float* xe = x + (long)lsrc[e] * FIN;
      float b0=0.f, b1v=0.f, b2v=0.f, b3v=0.f;
      #pragma unroll 4
      for (int i = 0; i < 20; ++i){
        int k = lane + 64 * i;
        float xv = xe[k];
        float4 ws = *(const float4*)(w_att + k * 8);
        b0 += xv * ws.x; b1v += xv * ws.y; b2v += xv * ws.z; b3v += xv * ws.w;
      }
      #pragma unroll
      for (int o = 32; o; o >>= 1){
        b0  += __shfl_xor(b0, o, 64);  b1v += __shfl_xor(b1v, o, 64);
        b2v += __shfl_xor(b2v, o, 64); b3v += __shfl_xor(b3v, o, 64);
      }
      if (lane == 0){ ev[0][e]=b0; ev[1][e]=b1v; ev[2][e]=b2v; ev[3][e]=b3v; }
    }
    __syncthreads();
    // softmax per head (wave w = head w)
    {
      float ad = adml[w];
      float m = -3.4e38f;
      for (int e = lane; e < ce; e += 64){
        float v = lrelu(ev[w][e] + ad);
        ev[w][e] = v;
        m = fmaxf(m, v);
      }
      #pragma unroll
      for (int o = 32; o; o >>= 1) m = fmaxf(m, __shfl_xor(m, o, 64));
      float ssum = 0.f;
      for (int e = lane; e < ce; e += 64){
        float a2 = expf(ev[w][e] - m);
        ev[w][e] = a2;
        ssum += a2;
      }
      #pragma unroll
      for (int o = 32; o; o >>= 1) ssum += __shfl_xor(ssum, o, 64);
      float inv = 1.f / (ssum + 1e-16f);
      for (int e = lane; e < ce; e += 64) ev[w][e] *= inv;
    }
    __syncthreads();
    // aggregate x rows per head
    {
      float acc[20];
      #pragma unroll
      for (int i = 0; i < 20; ++i) acc[i] = 0.f;
      for (int e = 0; e < ce; ++e){
        float al = ev[w][e];
        const float* xe = x + (long)lsrc[e] * FIN;
        #pragma unroll
        for (int i = 0; i < 20; ++i) acc[i] += al * xe[lane + 64 * i];
      }
      float* X1p = X1 + ((long)j * NHEAD + w) * FIN;
      #pragma unroll
      for (int i = 0; i < 20; ++i) X1p[lane + 64 * i] = acc[i];
    }
    __syncthreads();
  }
}

// K2 (k_d): tiny GEMM X1@W1 (block-diag per head), atomicAdd into h1 (L2-resident)
__global__ __launch_bounds__(256) void k_d(
    const float* __restrict__ X1, const float* __restrict__ W1,
    const int* __restrict__ E2cnt, const int* __restrict__ E2raw,
    float* __restrict__ h1){
  __shared__ float Wl[KCK][128];   // 32 KB
  __shared__ float Xl[KCK][16];    // 4 KB
  __shared__ int   S1l[MAX1];
  __shared__ int   n1s;
  int t = threadIdx.x, bid = blockIdx.x;
  if (t == 0) n1s = derive_S1(E2cnt, E2raw, S1l);
  int ct = bid & 7, kc = bid >> 3;
  int head = ct >> 1;
  int k0 = kc * KCK, c0 = ct * 128;
  for (int idx = t; idx < 2048; idx += 256){
    int r = idx >> 5, c4 = idx & 31;
    *(float4*)&Wl[r][c4 * 4] = *(const float4*)(W1 + (long)(k0 + r) * FH + c0 + c4 * 4);
  }
  __syncthreads();
  int n1 = n1s;
  int nRG = (n1 + 15) >> 4;
  int cth = t & 31, rth = t >> 5;
  for (int rg = 0; rg < nRG; ++rg){
    int r0 = rg * 16;
    __syncthreads();
    {
      int r = t & 15, kq = t >> 4;
      float4 v = make_float4(0.f, 0.f, 0.f, 0.f);
      if (r0 + r < n1)
        v = *(const float4*)(X1 + ((long)(r0 + r) * NHEAD + head) * FIN + k0 + kq * 4);
      Xl[kq * 4 + 0][r] = v.x;
      Xl[kq * 4 + 1][r] = v.y;
      Xl[kq * 4 + 2][r] = v.z;
      Xl[kq * 4 + 3][r] = v.w;
    }
    __syncthreads();
    float4 A0 = make_float4(0.f,0.f,0.f,0.f), A1 = A0;
    #pragma unroll 4
    for (int k = 0; k < KCK; ++k){
      float4 wv = *(const float4*)&Wl[k][cth * 4];
      float x0 = Xl[k][rth * 2], x1 = Xl[k][rth * 2 + 1];
      A0.x += x0 * wv.x; A0.y += x0 * wv.y; A0.z += x0 * wv.z; A0.w += x0 * wv.w;
      A1.x += x1 * wv.x; A1.y += x1 * wv.y; A1.z += x1 * wv.z; A1.w += x1 * wv.w;
    }
    int rb = r0 + rth * 2;
    float* dp = h1 + (long)rb * FH + c0 + cth * 4;
    if (rb < n1){
      atomicAdd(dp + 0, A0.x); atomicAdd(dp + 1, A0.y);
      atomicAdd(dp + 2, A0.z); atomicAdd(dp + 3, A0.w);
    }
    if (rb + 1 < n1){
      float* d1 = dp + FH;
      atomicAdd(d1 + 0, A1.x); atomicAdd(d1 + 1, A1.y);
      atomicAdd(d1 + 2, A1.z); atomicAdd(d1 + 3, A1.w);
    }
  }
}

// K3 (k_e): per S1 node: relu(h1+b1) -> k-split GEMV @ W2 -> gb
__global__ __launch_bounds__(1024) void k_e(
    const float* __restrict__ h1, const float* __restrict__ b1,
    const float* __restrict__ W2,
    const int* __restrict__ E2cnt, const int* __restrict__ E2raw,
    float* __restrict__ gb){
  __shared__ float h1row[FH];
  __shared__ float part[8][C2];
  __shared__ int   S1l[MAX1];
  __shared__ int   n1s;
  int t = threadIdx.x;
  if (t == 0) n1s = derive_S1(E2cnt, E2raw, S1l);
  __syncthreads();
  int n1 = n1s;
  for (int j = blockIdx.x; j < n1; j += gridDim.x){
    __syncthreads();
    if (t < 256){
      float4 s = *(const float4*)(h1 + (long)j * FH + 4 * t);
      float4 bv = *(const float4*)(b1 + 4 * t);
      s.x += bv.x; s.y += bv.y; s.z += bv.z; s.w += bv.w;
      s.x = s.x > 0.f ? s.x : 0.f;
      s.y = s.y > 0.f ? s.y : 0.f;
      s.z = s.z > 0.f ? s.z : 0.f;
      s.w = s.w > 0.f ? s.w : 0.f;
      *(float4*)(h1row + 4 * t) = s;
    }
    __syncthreads();
    {
      int col = t & 127, sl = t >> 7;
      const float* Wp = W2 + (long)(sl * 128) * C2 + col;
      const float* hp = h1row + sl * 128;
      float g = 0.f;
      #pragma unroll 16
      for (int k = 0; k < 128; ++k) g += hp[k] * Wp[(long)k * C2];
      part[sl][col] = g;
    }
    __syncthreads();
    if (t < C2){
      float s8 = 0.f;
      #pragma unroll
      for (int q = 0; q < 8; ++q) s8 += part[q][t];
      gb[j * C2 + t] = s8;
    }
  }
}

// K4 (k_final, 512 threads): derive E2/jl, layer-2 attention+softmax+aggregate, MLP head
__global__ __launch_bounds__(512) void k_final(
    const int* __restrict__ mip,
    const int* __restrict__ E2cnt, const int* __restrict__ E2raw,
    const float* __restrict__ gb,
    const float* __restrict__ as2, const float* __restrict__ ad2,
    const float* __restrict__ b2,
    const float* __restrict__ r1,
    const float* __restrict__ Wm2, const float* __restrict__ bm2,
    const float* __restrict__ Wp1, const float* __restrict__ bp1,
    const float* __restrict__ Wp2, const float* __restrict__ bp2,
    const float* __restrict__ Wp3, const float* __restrict__ bp3,
    float* __restrict__ out){
  __shared__ float al[MAXE2];
  __shared__ int   jl[MAXE2];
  __shared__ int   S1l[MAX1];
  __shared__ int   meta[2];                   // ne2, jmi
  __shared__ float feat[C2], r2s[C2], z1s[C2], z2s[32];
  __shared__ float p4[4][C2];
  __shared__ float p16[16][32];
  int t = threadIdx.x;
  if (t == 0){
    int n1 = derive_S1(E2cnt, E2raw, S1l);
    int ne2 = 0;
    for (int b = 0; b < NREG; ++b){
      int c = E2cnt[b];
      if (c < 0) c = 0; if (c > E2CAP) c = E2CAP;
      for (int s = 0; s < c; ++s){
        int v = E2raw[b * E2CAP + s];
        if (ne2 < MAXE2){
          int idx = 0;
          for (int k = 0; k < n1; ++k) if (S1l[k] == v){ idx = k; break; }
          jl[ne2++] = idx;
        }
      }
    }
    int mi = mip[0], jmi = 0;
    for (int k = 0; k < n1; ++k) if (S1l[k] == mi){ jmi = k; break; }
    meta[0] = ne2; meta[1] = jmi;
  }
  __syncthreads();
  int ne2 = meta[0], jmi = meta[1];
  int w = t >> 6, lane = t & 63;
  {
    int c = lane * 2;
    float v = gb[jmi * C2 + c] * ad2[c] + gb[jmi * C2 + c + 1] * ad2[c + 1];
    #pragma unroll
    for (int o = 32; o; o >>= 1) v += __shfl_xor(v, o, 64);
    float adv = v;
    for (int k = w; k < ne2; k += 8){
      int jj = jl[k];
      float u = gb[jj * C2 + c] * as2[c] + gb[jj * C2 + c + 1] * as2[c + 1];
      #pragma unroll
      for (int o = 32; o; o >>= 1) u += __shfl_xor(u, o, 64);
      if (lane == 0) al[k] = lrelu(u + adv);
    }
  }
  __syncthreads();
  if (t < 64){
    float m = -3.4e38f;
    for (int k = t; k < ne2; k += 64) m = fmaxf(m, al[k]);
    #pragma unroll
    for (int o = 32; o; o >>= 1) m = fmaxf(m, __shfl_xor(m, o, 64));
    float s = 0.f;
    for (int k = t; k < ne2; k += 64){
      float a2 = expf(al[k] - m);
      al[k] = a2;
      s += a2;
    }
    #pragma unroll
    for (int o = 32; o; o >>= 1) s += __shfl_xor(s, o, 64);
    float inv = 1.f / (s + 1e-16f);
    for (int k = t; k < ne2; k += 64) al[k] *= inv;
  }
  __syncthreads();
  int col = t & 127, sub = t >> 7;
  {
    float pr = 0.f;
    #pragma unroll 8
    for (int k = sub * 32; k < sub * 32 + 32; ++k) pr += r1[k] * Wm2[k * C2 + col];
    p4[sub][col] = pr;
    if (t < C2){
      float acc = 0.f;
      for (int k = 0; k < ne2; ++k) acc += al[k] * gb[jl[k] * C2 + t];
      float v = acc + b2[t];
      feat[t] = v > 0.f ? v : 0.f;
    }
  }
  __syncthreads();
  if (t < C2) r2s[t] = p4[0][t] + p4[1][t] + p4[2][t] + p4[3][t] + bm2[t];
  __syncthreads();
  {
    float acc = 0.f;
    #pragma unroll 8
    for (int k = sub * 64; k < sub * 64 + 64; ++k){
      float zv = (k < C2) ? feat[k] : r2s[k - C2];
      acc += zv * Wp1[k * C2 + col];
    }
    p4[sub][col] = acc;
  }
  __syncthreads();
  if (t < C2){
    float v = p4[0][t] + p4[1][t] + p4[2][t] + p4[3][t] + bp1[t];
    z1s[t] = v > 0.f ? v : 0.f;
  }
  __syncthreads();
  {
    int c2 = t & 31, sl = t >> 5;
    float acc = 0.f;
    #pragma unroll
    for (int k = sl * 8; k < sl * 8 + 8; ++k) acc += z1s[k] * Wp2[k * 32 + c2];
    p16[sl][c2] = acc;
  }
  __syncthreads();
  if (t < 32){
    float s = 0.f;
    #pragma unroll
    for (int q = 0; q < 16; ++q) s += p16[q][t];
    float v = s + bp2[t];
    z2s[t] = v > 0.f ? v : 0.f;
  }
  __syncthreads();
  if (t == 0){
    float acc = 0.f;
    for (int k = 0; k < 32; ++k) acc += z2s[k] * Wp3[k];
    out[0] = acc + bp3[0];
  }
}

extern "C" void kernel_launch(void* const* d_in, const int* in_sizes, int n_in,
                              void* d_out, int out_size, void* d_ws, size_t ws_size,
                              hipStream_t stream){
  const float* x   = (const float*)d_in[0];
  const int*   ei  = (const int*)d_in[1];
  const int*   mip = (const int*)d_in[2];
  const float* msd = (const float*)d_in[3];
  const float* Wm1 = (const float*)d_in[4];
  const float* bm1 = (const float*)d_in[5];
  const float* Wm2 = (const float*)d_in[6];
  const float* bm2 = (const float*)d_in[7];
  const float* W1  = (const float*)d_in[8];
  const float* as1 = (const float*)d_in[9];
  const float* ad1 = (const float*)d_in[10];
  const float* b1  = (const float*)d_in[11];
  const float* W2  = (const float*)d_in[12];
  const float* as2 = (const float*)d_in[13];
  const float* ad2 = (const float*)d_in[14];
  const float* b2  = (const float*)d_in[15];
  const float* Wp1 = (const float*)d_in[16];
  const float* bp1 = (const float*)d_in[17];
  const float* Wp2 = (const float*)d_in[18];
  const float* bp2 = (const float*)d_in[19];
  const float* Wp3 = (const float*)d_in[20];
  const float* bp3 = (const float*)d_in[21];
  float* out = (float*)d_out;

  char* q = (char*)d_ws;
  auto alloc = [&](size_t bytes) -> void* {
    void* r = (void*)q;
    q += (bytes + 255) & ~(size_t)255;
    return r;
  };
  int*   E2cnt = (int*)alloc(NREG * 4);
  int*   E2raw = (int*)alloc((size_t)NREG * E2CAP * 4);
  float* w_att = (float*)alloc((size_t)FIN * 8 * 4);               // 40 KB
  float* X1    = (float*)alloc((size_t)MAX1 * NHEAD * FIN * 4);    // 2.6 MB
  float* h1    = (float*)alloc((size_t)MAX1 * FH * 4);             // 512 KB
  float* gb    = (float*)alloc(MAX1 * C2 * 4);
  float* r1    = (float*)alloc(C2 * 4);

  k_pre  <<<PRE_B, 256, 0, stream>>>(ei, mip, W1, as1, ad1, msd, Wm1, bm1,
                                     E2cnt, E2raw, w_att, r1, (float4*)h1);
  k_bc   <<<16, 256, 0, stream>>>(x, ei, w_att, E2cnt, E2raw, X1);
  k_d    <<<D_B, 256, 0, stream>>>(X1, W1, E2cnt, E2raw, h1);
  k_e    <<<16, 1024, 0, stream>>>(h1, b1, W2, E2cnt, E2raw, gb);
  k_final<<<1, 512, 0, stream>>>(mip, E2cnt, E2raw, gb, as2, ad2, b2, r1,
                                 Wm2, bm2, Wp1, bp1, Wp2, bp2, Wp3, bp3, out);
}